// Round 7
// baseline (28.990 us; speedup 1.0000x reference)
//
#include <hip/hip_runtime.h>
#include <cmath>

// Problem constants (fixed by the reference)
#define B_ 256
#define I_ 1024
#define O_ 1024
#define CAP 256   // max CSR entries per o-row (mean 102, sd 9.6 -> 16 sigma)

// float -> bf16 bits, round-to-nearest-even (inputs finite after clamp)
__device__ inline unsigned f2bf(float f) {
  union { float f; unsigned u; } c;
  c.f = f;
  unsigned u = c.u;
  return (u + 0x7FFFu + ((u >> 16) & 1u)) >> 16;
}

// fast log(tanh(100|x|)) = log(1-t) - log(1+t), t = e^{-200|x|}  (HW exp/log)
// x==0: log(0) = -inf -> clamped to -1e30; exp(sum)=0 downstream (delta=0 case).
__device__ inline float fast_lt(float xv) {
  float z = 100.0f * fabsf(xv);
  float t = __expf(-2.0f * z);
  float lt = __logf(1.0f - t) - __logf(1.0f + t);
  return fmaxf(lt, -1e30f);
}

#define TBLKS ((B_ / 64) * (I_ / 16))  // 256 transpose blocks
#define CBLKS (O_ / 2)                 // 512 CSR blocks (2 o's each)

// ---------------------------------------------------------------------------
// Prep (one launch, blockIdx split):
//  blocks [0,TBLKS): xlT[i][b] = pack(lo=bf16(x[b][i]), hi=bf16(logtanh));
//                    i-major layout -> gather reads 256B contiguous per i.
//  blocks [TBLKS,+CBLKS): per-o CSR: entries[o][j] = pack(lo=i, hi=bf16(fc)),
//                    cnt[o]; deterministic ballot compaction (fixed order).
// ---------------------------------------------------------------------------
__global__ __launch_bounds__(256) void prep_sparse(
    const float* __restrict__ x, const float* __restrict__ vw,
    const float* __restrict__ fcw, unsigned* __restrict__ xlT,
    unsigned* __restrict__ entries, unsigned* __restrict__ cnt) {
  const int bid = blockIdx.x;
  const int t = threadIdx.x;

  if (bid < TBLKS) {
    // ---- transpose+convert: tile 64 b x 16 i ----
    const int i0 = (bid >> 2) * 16;
    const int b0 = (bid & 3) * 64;
    __shared__ unsigned tile[64][20];  // +4 pad
    const int r = t >> 2;              // b_loc 0..63
    const int c4 = (t & 3) * 4;        // i_loc 0,4,8,12
    float4 xv4 = *reinterpret_cast<const float4*>(&x[(size_t)(b0 + r) * I_ + i0 + c4]);
    float xa[4] = {xv4.x, xv4.y, xv4.z, xv4.w};
#pragma unroll
    for (int j = 0; j < 4; ++j)
      tile[r][c4 + j] = f2bf(xa[j]) | (f2bf(fast_lt(xa[j])) << 16);
    __syncthreads();
    const int il = t >> 4;             // 0..15
    const int bc = (t & 15) * 4;       // 0..60
    uint4 wv;
    wv.x = tile[bc + 0][il];
    wv.y = tile[bc + 1][il];
    wv.z = tile[bc + 2][il];
    wv.w = tile[bc + 3][il];
    *reinterpret_cast<uint4*>(&xlT[(size_t)(i0 + il) * B_ + b0 + bc]) = wv;
  } else {
    // ---- CSR build for o0, o0+1 ----
    const int o0 = (bid - TBLKS) * 2;
    __shared__ unsigned list_[CAP];
    __shared__ unsigned wcnt[4], wbs[4], totalc;
    const int w = t >> 6, lane = t & 63;
    for (int oo = 0; oo < 2; ++oo) {
      const int o = o0 + oo;
      if (t == 0) totalc = 0;
      __syncthreads();
#pragma unroll
      for (int s = 0; s < 4; ++s) {
        const int i = s * 256 + t;
        float v = vw[(size_t)o * I_ + i];
        float f = fcw[(size_t)o * I_ + i];
        bool p = v > 0.0f;
        unsigned long long m = __ballot(p);
        if (lane == 0) wcnt[w] = __popcll(m);
        __syncthreads();
        if (t == 0) {
          unsigned b = totalc;
#pragma unroll
          for (int k = 0; k < 4; ++k) { unsigned c = wcnt[k]; wbs[k] = b; b += c; }
          totalc = b;
        }
        __syncthreads();
        if (p) {
          unsigned pos = wbs[w] + __popcll(m & ((1ull << lane) - 1ull));
          if (pos < CAP) list_[pos] = (unsigned)i | (f2bf(f) << 16);
        }
        __syncthreads();
      }
      unsigned n = totalc > CAP ? CAP : totalc;
      if ((unsigned)t < n) entries[(size_t)o * CAP + t] = list_[t];
      if (t == 0) cnt[o] = n;
      __syncthreads();
    }
  }
}

// ---------------------------------------------------------------------------
// Sparse gather: grid (O/8, B/64), 512 threads = 8 waves.
// Wave w owns o = o_base + w (uniform per wave); lane owns b = b0 + lane.
// Inner loop (~102 iters): uniform CSR entry + coalesced 256B L2 gather of
// the packed (x,lt) pair; dot += x*fc (fp32 fma), slog += lt.
// Epilogue fused: delta = exp(slog), y = relu(dot*delta). No LDS, no barriers.
// ---------------------------------------------------------------------------
__global__ __launch_bounds__(512) void gather_sparse(
    const unsigned* __restrict__ xlT, const unsigned* __restrict__ entries,
    const unsigned* __restrict__ cnt, float* __restrict__ out) {
  const int t = threadIdx.x;
  const int o = blockIdx.x * 8 + (t >> 6);
  const int b = blockIdx.y * 64 + (t & 63);
  const unsigned n = cnt[o];
  const unsigned* __restrict__ ep = entries + (size_t)o * CAP;
  const unsigned* __restrict__ xp = xlT + b;  // + idx*256 per gather

  float dot = 0.0f, slog = 0.0f;
  unsigned j = 0;
  for (; j + 4 <= n; j += 4) {
    unsigned e0 = ep[j], e1 = ep[j + 1], e2 = ep[j + 2], e3 = ep[j + 3];
    unsigned p0 = xp[(e0 & 0xFFFFu) << 8];
    unsigned p1 = xp[(e1 & 0xFFFFu) << 8];
    unsigned p2 = xp[(e2 & 0xFFFFu) << 8];
    unsigned p3 = xp[(e3 & 0xFFFFu) << 8];
    dot = fmaf(__uint_as_float(p0 << 16), __uint_as_float(e0 & 0xFFFF0000u), dot);
    slog += __uint_as_float(p0 & 0xFFFF0000u);
    dot = fmaf(__uint_as_float(p1 << 16), __uint_as_float(e1 & 0xFFFF0000u), dot);
    slog += __uint_as_float(p1 & 0xFFFF0000u);
    dot = fmaf(__uint_as_float(p2 << 16), __uint_as_float(e2 & 0xFFFF0000u), dot);
    slog += __uint_as_float(p2 & 0xFFFF0000u);
    dot = fmaf(__uint_as_float(p3 << 16), __uint_as_float(e3 & 0xFFFF0000u), dot);
    slog += __uint_as_float(p3 & 0xFFFF0000u);
  }
  for (; j < n; ++j) {
    unsigned e = ep[j];
    unsigned p = xp[(e & 0xFFFFu) << 8];
    dot = fmaf(__uint_as_float(p << 16), __uint_as_float(e & 0xFFFF0000u), dot);
    slog += __uint_as_float(p & 0xFFFF0000u);
  }

  float d = __expf(slog);
  float y = fmaxf(dot * d, 0.0f);
  out[(size_t)b * O_ + o] = y;
  out[(size_t)B_ * O_ + (size_t)b * O_ + o] = d;
}

// ---------------------------------------------------------------------------
// fp32 fallback (workspace too small): inline log-tanh, fused epilogue
// ---------------------------------------------------------------------------
__global__ __launch_bounds__(256) void dual_gemm_f32(
    const float* __restrict__ x, const float* __restrict__ vw,
    const float* __restrict__ fcw, float* __restrict__ out) {
  const int on0 = blockIdx.x * 64;
  const int bm0 = blockIdx.y * 64;
  __shared__ float xs[32][68];
  __shared__ float ls[32][68];
  __shared__ float wsm[32][68];
  __shared__ float msh[32][68];
  const int t = threadIdx.x;
  const int tx = t & 15, ty = t >> 4;
  const int m0 = ty * 4, n0 = tx * 4;
  float accd[4][4] = {{0.f}};
  float accs[4][4] = {{0.f}};
  for (int kt = 0; kt < I_; kt += 32) {
#pragma unroll
    for (int j = 0; j < 8; ++j) {
      int f = j * 256 + t;
      int m = f >> 5;
      int kk = f & 31;
      int gk = kt + kk;
      float xv = x[(size_t)(bm0 + m) * I_ + gk];
      xs[kk][m] = xv;
      ls[kk][m] = fast_lt(xv);
      float vv = vw[(size_t)(on0 + m) * I_ + gk];
      float fv = fcw[(size_t)(on0 + m) * I_ + gk];
      float mk = vv > 0.0f ? 1.0f : 0.0f;
      wsm[kk][m] = fv * mk;
      msh[kk][m] = mk;
    }
    __syncthreads();
#pragma unroll
    for (int kk = 0; kk < 32; ++kk) {
      float4 xv = *reinterpret_cast<const float4*>(&xs[kk][m0]);
      float4 lv = *reinterpret_cast<const float4*>(&ls[kk][m0]);
      float4 wv = *reinterpret_cast<const float4*>(&wsm[kk][n0]);
      float4 mv = *reinterpret_cast<const float4*>(&msh[kk][n0]);
      float xa[4] = {xv.x, xv.y, xv.z, xv.w};
      float la[4] = {lv.x, lv.y, lv.z, lv.w};
      float wa[4] = {wv.x, wv.y, wv.z, wv.w};
      float ma[4] = {mv.x, mv.y, mv.z, mv.w};
#pragma unroll
      for (int i = 0; i < 4; ++i)
#pragma unroll
        for (int jj = 0; jj < 4; ++jj) {
          accd[i][jj] = fmaf(xa[i], wa[jj], accd[i][jj]);
          accs[i][jj] = fmaf(la[i], ma[jj], accs[i][jj]);
        }
    }
    __syncthreads();
  }
#pragma unroll
  for (int i = 0; i < 4; ++i) {
    int row = bm0 + m0 + i;
#pragma unroll
    for (int jj = 0; jj < 4; ++jj) {
      float delta = __expf(accs[i][jj]);
      out[(size_t)row * O_ + on0 + n0 + jj] = fmaxf(accd[i][jj] * delta, 0.0f);
      out[(size_t)B_ * O_ + (size_t)row * O_ + on0 + n0 + jj] = delta;
    }
  }
}

extern "C" void kernel_launch(void* const* d_in, const int* in_sizes, int n_in,
                              void* d_out, int out_size, void* d_ws,
                              size_t ws_size, hipStream_t stream) {
  const float* x = (const float*)d_in[0];
  const float* vw = (const float*)d_in[1];
  const float* fcw = (const float*)d_in[2];
  float* out = (float*)d_out;

  const size_t xlB = (size_t)B_ * I_ * 4;        // 1 MB packed (x,lt) pairs
  const size_t enB = (size_t)O_ * CAP * 4;       // 1 MB CSR entries
  const size_t cnB = (size_t)O_ * 4;             // 4 KB counts

  unsigned* xlT = (unsigned*)d_ws;
  unsigned* entries = (unsigned*)((char*)d_ws + xlB);
  unsigned* cnt = (unsigned*)((char*)d_ws + xlB + enB);

  if (ws_size >= xlB + enB + cnB) {
    prep_sparse<<<TBLKS + CBLKS, 256, 0, stream>>>(x, vw, fcw, xlT, entries, cnt);
    gather_sparse<<<dim3(O_ / 8, B_ / 64), 512, 0, stream>>>(xlT, entries, cnt, out);
  } else {
    dual_gemm_f32<<<dim3(O_ / 64, B_ / 64, 1), 256, 0, stream>>>(x, vw, fcw, out);
  }
}